// Round 17
// baseline (387.219 us; speedup 1.0000x reference)
//
#include <hip/hip_runtime.h>
#include <math.h>

// Problem constants
constexpr int kN = 25000;
constexpr int kE = 400000;
constexpr int kTaug = kE + kN;        // CSR slots incl self-loops = 425000
constexpr int kTpad = 425024;         // padded to tile boundary (13282*32)
constexpr int kNBLK = (kN + 255) / 256;   // 98 scan blocks

typedef __attribute__((ext_vector_type(8))) short bf16x8s;   // 8 bf16 (4 VGPRs)
typedef __attribute__((ext_vector_type(4))) float f32x4;

__device__ __forceinline__ unsigned short f2bf(float f) {
    unsigned u = __builtin_bit_cast(unsigned, f);
    unsigned r = (u + 0x7FFFu + ((u >> 16) & 1u)) >> 16;     // RNE
    return (unsigned short)r;
}
__device__ __forceinline__ float bf2f(unsigned short h) {
    unsigned u = ((unsigned)h) << 16;
    return __builtin_bit_cast(float, u);
}

// DPP helpers (CTRL must be compile-time constant)
template<int CTRL>
__device__ __forceinline__ float dpp_mov(float x) {
    int yi = __builtin_amdgcn_update_dpp(0, __builtin_bit_cast(int, x), CTRL, 0xF, 0xF, true);
    return __builtin_bit_cast(float, yi);
}
template<int CTRL>
__device__ __forceinline__ float dpp_add(float x) {
    return x + dpp_mov<CTRL>(x);
}

// ---------------- workspace layout (256B aligned) ----------------
constexpr size_t OFF_EAPART = 0;            // 1024*32 f32
constexpr size_t OFF_EAMEAN = 131072;       // 32 f32
constexpr size_t OFF_PART   = 131328;       // 98 i32 (scan partials)
constexpr size_t OFF_CURSOR = 131840;       // N i32
constexpr size_t OFF_CSRSRC = 231936;       // kTpad i32
constexpr size_t OFF_CSREID = 1932032;      // kTpad i32
constexpr size_t OFF_CSRDST = 3632128;      // kTpad i32
constexpr size_t OFF_ACC    = 5332224;      // N*256 f32 (atomic acc; reused as P)
constexpr size_t OFF_DEN    = 30932224;     // N*4 f32
constexpr size_t OFF_COUNTS = 31332224;     // N i32 (inside the memset region)
constexpr size_t MEMSET_BYTES = 31332224 + 100000 - 5332224;   // acc+den+counts
constexpr size_t OFF_HA     = 31432448;     // N*64 f32
constexpr size_t OFF_HB     = 37832448;     // N*64 f32
constexpr size_t OFF_XL     = 44232448;     // N*256 bf16
constexpr size_t OFF_XR     = 69832448;     // N*256 f32
constexpr size_t OFF_TAB    = 95432448;     // contiguous weight-frag tables (~426KB)
// element (u16) offsets within TAB:
constexpr int T_F1H = 0,      T_F1L = 8192,  T_F2H = 16384, T_F2L = 24576;
constexpr int T_EMBH = 32768, T_EMBL = 49152;
constexpr int T_L1H = 65536,  T_L1L = 81920, T_R1H = 98304, T_R1L = 114688;
constexpr int T_L2H = 131072, T_L2L = 147456, T_R2H = 163840, T_R2L = 180224;

// ---------------- edge_attr column mean ----------------
__global__ __launch_bounds__(256) void ea_colsum_part(const float* __restrict__ ea,
                                                      float* __restrict__ part)
{
    __shared__ float lds[256];
    const int tid = threadIdx.x;
    const int k = tid & 31, g = tid >> 5;
    float acc = 0.f;
    for (int r = blockIdx.x * 8 + g; r < kE; r += gridDim.x * 8)
        acc += ea[(size_t)r * 32 + k];
    lds[tid] = acc; __syncthreads();
    if (tid < 128) lds[tid] += lds[tid + 128]; __syncthreads();
    if (tid < 64)  lds[tid] += lds[tid + 64];  __syncthreads();
    if (tid < 32)  part[blockIdx.x * 32 + k] = lds[tid] + lds[tid + 32];
}

__global__ __launch_bounds__(256) void ea_colsum_final(const float* __restrict__ part,
                                                       float* __restrict__ ea_mean)
{
    __shared__ float lds[256];
    const int tid = threadIdx.x;
    const int k = tid & 31, g = tid >> 5;
    float acc = 0.f;
    for (int p = g; p < 1024; p += 8) acc += part[p * 32 + k];
    lds[tid] = acc; __syncthreads();
    if (tid < 128) lds[tid] += lds[tid + 128]; __syncthreads();
    if (tid < 64)  lds[tid] += lds[tid + 64];  __syncthreads();
    if (tid < 32)  ea_mean[k] = (lds[tid] + lds[tid + 32]) * (1.0f / (float)kE);
}

// ---------------- We -> frag-swizzled bf16 hi/lo (edge_logit tables) ----------------
__global__ __launch_bounds__(256) void we_swizzle(const float* __restrict__ W1,
                                                  const float* __restrict__ W2,
                                                  unsigned short* __restrict__ tab)
{
    const int b = blockIdx.x;                 // 32 blocks: layer*16 + nt*4 + w
    const int layer = b >> 4, nt = (b >> 2) & 3, w = b & 3;
    const float* W = layer ? W2 : W1;
    unsigned short* H = tab + (layer ? T_F2H : T_F1H);
    unsigned short* L = tab + (layer ? T_F2L : T_F1L);
    const int tid = threadIdx.x;
    const int lane = tid & 63, jh = tid >> 6;
    const int c = w * 64 + nt * 16 + (lane & 15);
    const int kbase = (lane >> 4) * 8;
#pragma unroll
    for (int t = 0; t < 2; t++) {
        const int j = jh * 2 + t;
        const float f = W[(kbase + j) * 256 + c];
        const unsigned short hb = f2bf(f);
        const int idx = ((nt * 4 + w) * 64 + lane) * 8 + j;
        H[idx] = hb;
        L[idx] = f2bf(f - bf2f(hb));
    }
}

// ---------------- merged GEMM-weight frag tables (emb + 4 layer weights) ----------------
__global__ __launch_bounds__(256) void w_tables(const float* __restrict__ embW,
                                                const float* __restrict__ wl1,
                                                const float* __restrict__ wr1,
                                                const float* __restrict__ wl2,
                                                const float* __restrict__ wr2,
                                                unsigned short* __restrict__ tab)
{
    const int b = blockIdx.x, tid = threadIdx.x;
    const float* W; int KO, KCH, idx; unsigned short *H, *L;
    if (b < 32) {                 // emb: 4 ctiles x 4 kchunks = 8192 elems
        W = embW; KO = 64; KCH = 4; idx = b * 256 + tid;
        H = tab + T_EMBH; L = tab + T_EMBL;
    } else {                      // 4 tables of 16 ctiles x 2 kchunks = 16384 elems
        const int t = (b - 32) >> 6, r = (b - 32) & 63;
        idx = r * 256 + tid; KO = 256; KCH = 2;
        if      (t == 0) { W = wl1; H = tab + T_L1H; L = tab + T_L1L; }
        else if (t == 1) { W = wr1; H = tab + T_R1H; L = tab + T_R1L; }
        else if (t == 2) { W = wl2; H = tab + T_L2H; L = tab + T_L2L; }
        else             { W = wr2; H = tab + T_R2H; L = tab + T_R2L; }
    }
    const int j = idx & 7;
    const int lane = (idx >> 3) & 63;
    const int t2 = idx >> 9;
    const int ct = t2 / KCH;
    const int c = ct * 16 + (lane & 15);
    const int k = (t2 - ct * KCH) * 32 + (lane >> 4) * 8 + j;
    const float f = W[k * KO + c];
    const unsigned short hb = f2bf(f);
    H[idx] = hb;
    L[idx] = f2bf(f - bf2f(hb));
}

// ---------------- MFMA dense GEMM (single output, fp32 out) ----------------
template<int KI, int KO, int CSPLIT>
__global__ __launch_bounds__(256) void mfma_gemm_bias(
    const float* __restrict__ A,
    const unsigned short* __restrict__ WH, const unsigned short* __restrict__ WL,
    const float* __restrict__ bias, float* __restrict__ out, int M)
{
    constexpr int KCH = KI / 32;
    constexpr int CT  = KO / 16;
    constexpr int CTP = CT / CSPLIT;
    const int tid = threadIdx.x;
    const int w = tid >> 6, lane = tid & 63;
    const int rowblk = blockIdx.x / CSPLIT;
    const int csel   = blockIdx.x % CSPLIT;
    const int row0 = rowblk * 64 + w * 16;
    const int rr = lane & 15, kg = lane >> 4;
    const int arow = min(row0 + rr, M - 1);

    bf16x8s Ah[KCH], Al[KCH];
#pragma unroll
    for (int kk = 0; kk < KCH; kk++) {
        const float4 f0 = *(const float4*)&A[(size_t)arow * KI + kk * 32 + kg * 8];
        const float4 f1 = *(const float4*)&A[(size_t)arow * KI + kk * 32 + kg * 8 + 4];
        const float fv[8] = {f0.x, f0.y, f0.z, f0.w, f1.x, f1.y, f1.z, f1.w};
#pragma unroll
        for (int j = 0; j < 8; j++) {
            const unsigned short hb = f2bf(fv[j]);
            Ah[kk][j] = (short)hb;
            Al[kk][j] = (short)f2bf(fv[j] - bf2f(hb));
        }
    }
    const int rbase = kg * 4;
#pragma unroll
    for (int cti = 0; cti < CTP; cti++) {
        const int ct = csel * CTP + cti;
        f32x4 acc = {0.f, 0.f, 0.f, 0.f};
#pragma unroll
        for (int kk = 0; kk < KCH; kk++) {
            const int bidx = ((ct * KCH + kk) * 64 + lane) * 8;
            const bf16x8s Bh = *(const bf16x8s*)&WH[bidx];
            const bf16x8s Bl = *(const bf16x8s*)&WL[bidx];
            acc = __builtin_amdgcn_mfma_f32_16x16x32_bf16(Ah[kk], Bh, acc, 0, 0, 0);
            acc = __builtin_amdgcn_mfma_f32_16x16x32_bf16(Ah[kk], Bl, acc, 0, 0, 0);
            acc = __builtin_amdgcn_mfma_f32_16x16x32_bf16(Al[kk], Bh, acc, 0, 0, 0);
        }
        const float bv = bias[ct * 16 + rr];
#pragma unroll
        for (int r = 0; r < 4; r++) {
            const int row = row0 + rbase + r;
            if (row < M) out[(size_t)row * KO + ct * 16 + rr] = acc[r] + bv;
        }
    }
}

// ---------------- MFMA dense GEMM, dual output: outA = bf16 (xl), outB = fp32 (xr) ----------------
template<int KI, int KO, int CSPLIT>
__global__ __launch_bounds__(256) void mfma_gemm_bias2(
    const float* __restrict__ A,
    const unsigned short* __restrict__ WHa, const unsigned short* __restrict__ WLa,
    const unsigned short* __restrict__ WHb, const unsigned short* __restrict__ WLb,
    const float* __restrict__ biasA, const float* __restrict__ biasB,
    unsigned short* __restrict__ outA, float* __restrict__ outB, int M)
{
    constexpr int KCH = KI / 32;
    constexpr int CT  = KO / 16;
    constexpr int CTP = CT / CSPLIT;
    const int tid = threadIdx.x;
    const int w = tid >> 6, lane = tid & 63;
    const int rowblk = blockIdx.x / CSPLIT;
    const int csel   = blockIdx.x % CSPLIT;
    const int row0 = rowblk * 64 + w * 16;
    const int rr = lane & 15, kg = lane >> 4;
    const int arow = min(row0 + rr, M - 1);

    bf16x8s Ah[KCH], Al[KCH];
#pragma unroll
    for (int kk = 0; kk < KCH; kk++) {
        const float4 f0 = *(const float4*)&A[(size_t)arow * KI + kk * 32 + kg * 8];
        const float4 f1 = *(const float4*)&A[(size_t)arow * KI + kk * 32 + kg * 8 + 4];
        const float fv[8] = {f0.x, f0.y, f0.z, f0.w, f1.x, f1.y, f1.z, f1.w};
#pragma unroll
        for (int j = 0; j < 8; j++) {
            const unsigned short hb = f2bf(fv[j]);
            Ah[kk][j] = (short)hb;
            Al[kk][j] = (short)f2bf(fv[j] - bf2f(hb));
        }
    }
    const int rbase = kg * 4;
#pragma unroll
    for (int cti = 0; cti < CTP; cti++) {
        const int ct = csel * CTP + cti;
        // A output (xl, stored bf16)
        {
            f32x4 acc = {0.f, 0.f, 0.f, 0.f};
#pragma unroll
            for (int kk = 0; kk < KCH; kk++) {
                const int bidx = ((ct * KCH + kk) * 64 + lane) * 8;
                const bf16x8s Bh = *(const bf16x8s*)&WHa[bidx];
                const bf16x8s Bl = *(const bf16x8s*)&WLa[bidx];
                acc = __builtin_amdgcn_mfma_f32_16x16x32_bf16(Ah[kk], Bh, acc, 0, 0, 0);
                acc = __builtin_amdgcn_mfma_f32_16x16x32_bf16(Ah[kk], Bl, acc, 0, 0, 0);
                acc = __builtin_amdgcn_mfma_f32_16x16x32_bf16(Al[kk], Bh, acc, 0, 0, 0);
            }
            const float bv = biasA[ct * 16 + rr];
#pragma unroll
            for (int r = 0; r < 4; r++) {
                const int row = row0 + rbase + r;
                if (row < M) outA[(size_t)row * KO + ct * 16 + rr] = f2bf(acc[r] + bv);
            }
        }
        // B output (xr, fp32)
        {
            f32x4 acc = {0.f, 0.f, 0.f, 0.f};
#pragma unroll
            for (int kk = 0; kk < KCH; kk++) {
                const int bidx = ((ct * KCH + kk) * 64 + lane) * 8;
                const bf16x8s Bh = *(const bf16x8s*)&WHb[bidx];
                const bf16x8s Bl = *(const bf16x8s*)&WLb[bidx];
                acc = __builtin_amdgcn_mfma_f32_16x16x32_bf16(Ah[kk], Bh, acc, 0, 0, 0);
                acc = __builtin_amdgcn_mfma_f32_16x16x32_bf16(Ah[kk], Bl, acc, 0, 0, 0);
                acc = __builtin_amdgcn_mfma_f32_16x16x32_bf16(Al[kk], Bh, acc, 0, 0, 0);
            }
            const float bv = biasB[ct * 16 + rr];
#pragma unroll
            for (int r = 0; r < 4; r++) {
                const int row = row0 + rbase + r;
                if (row < M) outB[(size_t)row * KO + ct * 16 + rr] = acc[r] + bv;
            }
        }
    }
}

// ---------------- CSR build ----------------
__global__ __launch_bounds__(256) void count_edges(const int* __restrict__ ei,
                                                   int* __restrict__ counts)
{
    int e = blockIdx.x * 256 + threadIdx.x;
    if (e < kE) atomicAdd(&counts[ei[kE + e]], 1);
}

// 3-phase parallel scan: counts(+1 self-loop) -> exclusive prefix in cursor
__global__ __launch_bounds__(256) void scan_part(const int* __restrict__ counts,
                                                 int* __restrict__ cursor,
                                                 int* __restrict__ partials)
{
    __shared__ int lds[256];
    const int tid = threadIdx.x;
    const int i = blockIdx.x * 256 + tid;
    const int v = (i < kN) ? counts[i] + 1 : 0;   // +1 = self-loop slot
    lds[tid] = v; __syncthreads();
    for (int d = 1; d < 256; d <<= 1) {
        int t = (tid >= d) ? lds[tid - d] : 0;
        __syncthreads();
        lds[tid] += t;
        __syncthreads();
    }
    if (i < kN) cursor[i] = lds[tid] - v;          // block-local exclusive
    if (tid == 255) partials[blockIdx.x] = lds[255];
}

__global__ __launch_bounds__(128) void scan_mid(int* __restrict__ partials)
{
    __shared__ int lds[128];
    const int tid = threadIdx.x;
    const int v = (tid < kNBLK) ? partials[tid] : 0;
    lds[tid] = v; __syncthreads();
    for (int d = 1; d < 128; d <<= 1) {
        int t = (tid >= d) ? lds[tid - d] : 0;
        __syncthreads();
        lds[tid] += t;
        __syncthreads();
    }
    if (tid < kNBLK) partials[tid] = lds[tid] - v; // exclusive block prefix
}

__global__ __launch_bounds__(256) void scan_add(int* __restrict__ cursor,
                                                const int* __restrict__ partials)
{
    const int i = blockIdx.x * 256 + threadIdx.x;
    if (i < kN) cursor[i] += partials[blockIdx.x];
}

// scatter + pad slots [kTaug, kTpad) with inert entries
__global__ __launch_bounds__(256) void scatter_kernel(const int* __restrict__ ei,
                                                      int* __restrict__ cursor,
                                                      int* __restrict__ csr_src,
                                                      int* __restrict__ csr_eid,
                                                      int* __restrict__ csr_dst)
{
    int gid = blockIdx.x * 256 + threadIdx.x;
    if (gid < kE) {
        int s = ei[gid];
        int d = ei[kE + gid];
        int p = atomicAdd(&cursor[d], 1);
        csr_src[p] = s;
        csr_eid[p] = gid;
        csr_dst[p] = d;
    } else if (gid < kTaug) {
        int n = gid - kE;
        int p = atomicAdd(&cursor[n], 1);
        csr_src[p] = n;
        csr_eid[p] = kE;   // sentinel: self-loop
        csr_dst[p] = n;
    } else if (gid < kTpad) {
        csr_src[gid] = 0;
        csr_eid[gid] = kE;       // sentinel (reads eamean; contribution masked to 0)
        csr_dst[gid] = kN - 1;
    }
}

// ---------------- Fused pass: per-edge attention + per-node aggregation ----------------
// R16: single chain traversal per tile — both halves' MFMA up-front into a
// full ep_lds[32][257], ALL 32 xl gathers in flight, four lockstep exchange
// reduces, 4 exps, one LDS pe publish, single ordered accumulate.
// (R13/14/15 showed the kernel is gather-LATENCY-bound: chain count is the lever.)
__global__ __launch_bounds__(256) void edge_logit_aggr_kernel(
    const unsigned short* __restrict__ xl, const float* __restrict__ xr,
    const float* __restrict__ ea, const float* __restrict__ eamean,
    const unsigned short* __restrict__ fragh, const unsigned short* __restrict__ fragl,
    const float* __restrict__ att,
    const int* __restrict__ csr_src, const int* __restrict__ csr_dst,
    const int* __restrict__ csr_eid,
    float* __restrict__ accbuf, float* __restrict__ denbuf)
{
    constexpr int ROWS = 40;                       // padded ea row (shorts), 80B
    constexpr int EPP  = 257;                      // padded ep row (floats)
    __shared__ __align__(16) unsigned short ea_hi[32 * ROWS];
    __shared__ __align__(16) unsigned short ea_lo[32 * ROWS];
    __shared__ __align__(16) float ep_lds[32 * EPP];     // full 32-edge tile
    __shared__ __align__(16) float lds_pe[4][32];
    const int tid  = threadIdx.x;
    const int w    = tid >> 6;
    const int lane = tid & 63;
    const int b0   = blockIdx.x * 32;

    // B fragments: 8 coalesced b128 loads from pre-swizzled tables
    bf16x8s bh[4], bl[4];
#pragma unroll
    for (int nt = 0; nt < 4; nt++) {
        const int idx = ((nt * 4 + w) * 64 + lane) * 8;
        bh[nt] = *(const bf16x8s*)&fragh[idx];
        bl[nt] = *(const bf16x8s*)&fragl[idx];
    }
    const float att_r = att[tid];
    const int aoff  = (lane & 15) * ROWS + (lane >> 4) * 8;
    const int cbase = w * 64 + (lane & 15);
    const int rbase = (lane >> 4) * 4;

    // stage ea rows (csr padded to kTpad: no clamp needed)
    {
        const int j = tid >> 3, q = tid & 7;
        const int eid = csr_eid[b0 + j];
        const float4* srcp = (eid < kE) ? (const float4*)(ea + (size_t)eid * 32)
                                        : (const float4*)eamean;
        const float4 f = srcp[q];
        const unsigned short h0 = f2bf(f.x), h1 = f2bf(f.y),
                             h2 = f2bf(f.z), h3 = f2bf(f.w);
        const unsigned short g0 = f2bf(f.x - bf2f(h0)), g1 = f2bf(f.y - bf2f(h1)),
                             g2 = f2bf(f.z - bf2f(h2)), g3 = f2bf(f.w - bf2f(h3));
        const unsigned long long ph =
            (unsigned long long)h0 | ((unsigned long long)h1 << 16) |
            ((unsigned long long)h2 << 32) | ((unsigned long long)h3 << 48);
        const unsigned long long pl =
            (unsigned long long)g0 | ((unsigned long long)g1 << 16) |
            ((unsigned long long)g2 << 32) | ((unsigned long long)g3 << 48);
        *(unsigned long long*)&ea_hi[j * ROWS + q * 4] = ph;
        *(unsigned long long*)&ea_lo[j * ROWS + q * 4] = pl;
    }
    __syncthreads();   // the ONLY cross-wave dependency: staging -> MFMA A-reads

    // ---- MFMA both row halves -> ep_lds[32][257] (wave-private columns) ----
    {
        const bf16x8s ah0 = *(const bf16x8s*)&ea_hi[aoff];
        const bf16x8s ah1 = *(const bf16x8s*)&ea_hi[16 * ROWS + aoff];
        const bf16x8s al0 = *(const bf16x8s*)&ea_lo[aoff];
        const bf16x8s al1 = *(const bf16x8s*)&ea_lo[16 * ROWS + aoff];
#pragma unroll
        for (int nt = 0; nt < 4; nt++) {
            f32x4 a0 = {0.f, 0.f, 0.f, 0.f};
            a0 = __builtin_amdgcn_mfma_f32_16x16x32_bf16(ah0, bh[nt], a0, 0, 0, 0);
            a0 = __builtin_amdgcn_mfma_f32_16x16x32_bf16(ah0, bl[nt], a0, 0, 0, 0);
            a0 = __builtin_amdgcn_mfma_f32_16x16x32_bf16(al0, bh[nt], a0, 0, 0, 0);
            f32x4 a1 = {0.f, 0.f, 0.f, 0.f};
            a1 = __builtin_amdgcn_mfma_f32_16x16x32_bf16(ah1, bh[nt], a1, 0, 0, 0);
            a1 = __builtin_amdgcn_mfma_f32_16x16x32_bf16(ah1, bl[nt], a1, 0, 0, 0);
            a1 = __builtin_amdgcn_mfma_f32_16x16x32_bf16(al1, bh[nt], a1, 0, 0, 0);
            const int cc = cbase + nt * 16;
#pragma unroll
            for (int r = 0; r < 4; r++) {
                ep_lds[(rbase + r) * EPP + cc]        = a0[r];
                ep_lds[(16 + rbase + r) * EPP + cc]   = a1[r];
            }
        }
    }
    // no barrier: wave w reads only the ep_lds columns it wrote

    // ---- indices (scalar pipe) + all 32 gathers in flight ----
    int sv_s[32], dv_s[32];
#pragma unroll
    for (int u = 0; u < 32; u++) {
        sv_s[u] = csr_src[b0 + u];
        dv_s[u] = csr_dst[b0 + u];
    }
    float xls[32], c[32];
#pragma unroll
    for (int u = 0; u < 32; u++) {
        const unsigned short* __restrict__ xlp = xl + (size_t)sv_s[u] * 256;
        xls[u] = bf2f(xlp[tid]);                   // 32 bf16 gathers in flight
    }
#pragma unroll
    for (int u = 0; u < 32; u++) {
        const float* __restrict__ xrp = xr + (size_t)dv_s[u] * 256;
        const float xrr = xrp[tid];
        float v = xls[u] + xrr + ep_lds[u * EPP + tid];
        v = fmaxf(v, 0.2f * v);                    // leaky_relu 0.2
        c[u] = att_r * v;
    }

    // ---- four lockstep multi-value exchange reduces (8 values each) ----
    float n[16];
    {   const bool s = lane & 1;
#pragma unroll
        for (int p = 0; p < 16; p++) {
            const float x0 = s ? c[2 * p + 1] : c[2 * p];
            const float x1 = s ? c[2 * p] : c[2 * p + 1];
            n[p] = x0 + dpp_mov<0xB1>(x1);         // value-id bit0 = lane bit0
        }
    }
    float m[8];
    {   const bool s = lane & 2;
#pragma unroll
        for (int p = 0; p < 8; p++) {
            const float x0 = s ? n[2 * p + 1] : n[2 * p];
            const float x1 = s ? n[2 * p] : n[2 * p + 1];
            m[p] = x0 + dpp_mov<0x4E>(x1);         // value-id bit1 = lane bit1
        }
    }
    float r[4];
    {   const bool s = lane & 32;
#pragma unroll
        for (int t = 0; t < 4; t++) {
            const float o = __shfl_xor(s ? m[2 * t] : m[2 * t + 1], 32);
            r[t] = (s ? m[2 * t + 1] : m[2 * t]) + o;   // value-id bit2 = lane bit5
        }
    }
#pragma unroll
    for (int t = 0; t < 4; t++) {
        r[t] = dpp_add<0x124>(r[t]);               // row_ror:4
        r[t] = dpp_add<0x128>(r[t]);               // row_ror:8
        r[t] += __shfl_xor(r[t], 16);
    }
    // lane holds full logits for edges 8t + u0, u0 = (l&3)|((l>>3)&4)
    float pe_r[4];
#pragma unroll
    for (int t = 0; t < 4; t++) pe_r[t] = __expf(r[t]);

    // pe publish via LDS (lds_pe[w] wave-private: no barrier)
    if ((lane & 0x1C) == 0) {
        const int slot = (lane & 3) | ((lane >> 3) & 4);
#pragma unroll
        for (int t = 0; t < 4; t++)
            lds_pe[w][t * 8 + slot] = pe_r[t];
    }
    float pu[32];
#pragma unroll
    for (int q = 0; q < 8; q++) {
        const float4 p = *(const float4*)&lds_pe[w][q * 4];
        pu[q * 4 + 0] = p.x; pu[q * 4 + 1] = p.y;
        pu[q * 4 + 2] = p.z; pu[q * 4 + 3] = p.w;
    }
    if (b0 + 32 > kTaug) {                         // tail: zero padded edges
#pragma unroll
        for (int u = 0; u < 32; u++)
            if (b0 + u >= kTaug) pu[u] = 0.f;
    }

    // ---- single ordered segmented accumulate over the whole tile ----
    int   cur_dst = dv_s[0];
    float den_p = 0.f, acc_p = 0.f;
#pragma unroll
    for (int u = 0; u < 32; u++) {
        if (dv_s[u] != cur_dst) {
            atomicAdd(&accbuf[(size_t)cur_dst * 256 + tid], acc_p);
            if (lane == 0) atomicAdd(&denbuf[cur_dst * 4 + w], den_p);
            acc_p = 0.f; den_p = 0.f; cur_dst = dv_s[u];
        }
        acc_p += pu[u] * xls[u];
        den_p += pu[u];
    }
    atomicAdd(&accbuf[(size_t)cur_dst * 256 + tid], acc_p);
    if (lane == 0) atomicAdd(&denbuf[cur_dst * 4 + w], den_p);
}

// ---------------- finalize: h = relu(mean_h(acc/den) + bias); optionally re-zero acc/den ----------------
template<bool ZERO>
__global__ __launch_bounds__(256) void gat_finalize(
    float* __restrict__ accbuf, float* __restrict__ denbuf,
    const float* __restrict__ gbias, float* __restrict__ h_out)
{
    __shared__ float red[256];
    const int tid = threadIdx.x;
    const int n = blockIdx.x;
    red[tid] = accbuf[(size_t)n * 256 + tid] / denbuf[n * 4 + (tid >> 6)];
    if (ZERO) {
        accbuf[(size_t)n * 256 + tid] = 0.f;
        if ((tid & 63) == 0) denbuf[n * 4 + (tid >> 6)] = 0.f;
    }
    __syncthreads();
    if (tid < 64) {
        float sres = red[tid] + red[tid + 64] + red[tid + 128] + red[tid + 192];
        h_out[n * 64 + tid] = fmaxf(0.25f * sres + gbias[tid], 0.f);
    }
}

// ---------------- node head: P[n][0:16]=h@W13[0:64], P[n][16:32]=h@W13[64:128] ----------------
__global__ __launch_bounds__(256) void node_head_kernel(
    const float* __restrict__ h, const float* __restrict__ intW,
    const float* __restrict__ impW, float* __restrict__ P)
{
    const int tid = threadIdx.x;
    const int w = tid >> 6, lane = tid & 63;
    const int row0 = blockIdx.x * 64 + w * 16;
    const int rr = lane & 15;
    const int kg = lane >> 4;

    bf16x8s Bh[2][2], Bl[2][2];
#pragma unroll
    for (int ct = 0; ct < 2; ct++) {
#pragma unroll
        for (int kk = 0; kk < 2; kk++) {
            const int kbase = ct * 64 + kk * 32 + kg * 8;
#pragma unroll
            for (int j = 0; j < 8; j++) {
                const int k = kbase + j;
                float wv;
                if (rr < 12)       wv = intW[k * 12 + rr];
                else if (rr == 12) wv = impW[k];
                else               wv = 0.f;
                const unsigned short hb = f2bf(wv);
                Bh[ct][kk][j] = (short)hb;
                Bl[ct][kk][j] = (short)f2bf(wv - bf2f(hb));
            }
        }
    }

    const int arow = min(row0 + rr, kN - 1);
    bf16x8s Ah[2], Al[2];
#pragma unroll
    for (int kk = 0; kk < 2; kk++) {
        const float4 f0 = *(const float4*)&h[arow * 64 + kk * 32 + kg * 8];
        const float4 f1 = *(const float4*)&h[arow * 64 + kk * 32 + kg * 8 + 4];
        const float fv[8] = {f0.x, f0.y, f0.z, f0.w, f1.x, f1.y, f1.z, f1.w};
#pragma unroll
        for (int j = 0; j < 8; j++) {
            const unsigned short hb = f2bf(fv[j]);
            Ah[kk][j] = (short)hb;
            Al[kk][j] = (short)f2bf(fv[j] - bf2f(hb));
        }
    }

#pragma unroll
    for (int ct = 0; ct < 2; ct++) {
        f32x4 acc = {0.f, 0.f, 0.f, 0.f};
#pragma unroll
        for (int kk = 0; kk < 2; kk++) {
            acc = __builtin_amdgcn_mfma_f32_16x16x32_bf16(Ah[kk], Bh[ct][kk], acc, 0, 0, 0);
            acc = __builtin_amdgcn_mfma_f32_16x16x32_bf16(Ah[kk], Bl[ct][kk], acc, 0, 0, 0);
            acc = __builtin_amdgcn_mfma_f32_16x16x32_bf16(Al[kk], Bh[ct][kk], acc, 0, 0, 0);
        }
        const int crow0 = kg * 4;
#pragma unroll
        for (int r = 0; r < 4; r++) {
            const int row = row0 + crow0 + r;
            if (row < kN) P[row * 32 + ct * 16 + rr] = acc[r];
        }
    }
}

// ---------------- edge out: Q = relu(ea)@W13[128:160]; out = Q + P_src + P_dst + b ----------------
__global__ __launch_bounds__(256) void edge_out_kernel(
    const float* __restrict__ ea, const int* __restrict__ ei,
    const float* __restrict__ P,
    const float* __restrict__ intW, const float* __restrict__ intb,
    const float* __restrict__ impW, const float* __restrict__ impb,
    float* __restrict__ out)
{
    constexpr int ROWS = 40;
    __shared__ __align__(16) unsigned short ehi[4][16 * ROWS];
    __shared__ __align__(16) unsigned short elo[4][16 * ROWS];
    const int tid = threadIdx.x;
    const int w = tid >> 6, lane = tid & 63;
    const int e0 = blockIdx.x * 64 + w * 16;
    const int rr = lane & 15, kg = lane >> 4;

    bf16x8s Bh, Bl;
#pragma unroll
    for (int j = 0; j < 8; j++) {
        const int k = 128 + kg * 8 + j;
        float wv;
        if (rr < 12)       wv = intW[k * 12 + rr];
        else if (rr == 12) wv = impW[k];
        else               wv = 0.f;
        const unsigned short hb = f2bf(wv);
        Bh[j] = (short)hb;
        Bl[j] = (short)f2bf(wv - bf2f(hb));
    }

    {
        const int j = lane >> 2, q = lane & 3;
        const float4* src = (const float4*)&ea[(size_t)(e0 + j) * 32 + q * 8];
        const float4 f0 = src[0], f1 = src[1];
        const float fv[8] = {fmaxf(f0.x, 0.f), fmaxf(f0.y, 0.f), fmaxf(f0.z, 0.f), fmaxf(f0.w, 0.f),
                             fmaxf(f1.x, 0.f), fmaxf(f1.y, 0.f), fmaxf(f1.z, 0.f), fmaxf(f1.w, 0.f)};
        unsigned long long ph0 = 0, pl0 = 0, ph1 = 0, pl1 = 0;
#pragma unroll
        for (int t = 0; t < 4; t++) {
            const unsigned short hb = f2bf(fv[t]);
            const unsigned short lb = f2bf(fv[t] - bf2f(hb));
            ph0 |= (unsigned long long)hb << (16 * t);
            pl0 |= (unsigned long long)lb << (16 * t);
        }
#pragma unroll
        for (int t = 0; t < 4; t++) {
            const unsigned short hb = f2bf(fv[4 + t]);
            const unsigned short lb = f2bf(fv[4 + t] - bf2f(hb));
            ph1 |= (unsigned long long)hb << (16 * t);
            pl1 |= (unsigned long long)lb << (16 * t);
        }
        *(unsigned long long*)&ehi[w][j * ROWS + q * 8]     = ph0;
        *(unsigned long long*)&ehi[w][j * ROWS + q * 8 + 4] = ph1;
        *(unsigned long long*)&elo[w][j * ROWS + q * 8]     = pl0;
        *(unsigned long long*)&elo[w][j * ROWS + q * 8 + 4] = pl1;
    }
    __syncthreads();

    const int aoff = rr * ROWS + kg * 8;
    const bf16x8s Ah = *(const bf16x8s*)&ehi[w][aoff];
    const bf16x8s Al = *(const bf16x8s*)&elo[w][aoff];
    f32x4 q = {0.f, 0.f, 0.f, 0.f};
    q = __builtin_amdgcn_mfma_f32_16x16x32_bf16(Ah, Bh, q, 0, 0, 0);
    q = __builtin_amdgcn_mfma_f32_16x16x32_bf16(Ah, Bl, q, 0, 0, 0);
    q = __builtin_amdgcn_mfma_f32_16x16x32_bf16(Al, Bh, q, 0, 0, 0);

    if (rr < 13) {
        const float bv = (rr < 12) ? intb[rr] : impb[0];
#pragma unroll
        for (int r = 0; r < 4; r++) {
            const int e = e0 + kg * 4 + r;
            const int s = ei[e], d = ei[kE + e];
            const float val = q[r] + P[s * 32 + rr] + P[d * 32 + 16 + rr] + bv;
            if (rr < 12) out[(size_t)e * 12 + rr] = val;
            else         out[(size_t)kE * 12 + e] = 1.f / (1.f + __expf(-val));
        }
    }
}

// ---------------- launch ----------------
extern "C" void kernel_launch(void* const* d_in, const int* in_sizes, int n_in,
                              void* d_out, int out_size, void* d_ws, size_t ws_size,
                              hipStream_t stream)
{
    (void)in_sizes; (void)n_in; (void)out_size; (void)ws_size;

    const float* x      = (const float*)d_in[0];
    const int*   ei     = (const int*)d_in[1];
    const float* ea     = (const float*)d_in[2];
    const float* emb_W  = (const float*)d_in[3];
    const float* emb_b  = (const float*)d_in[4];
    const float* g1_Wl  = (const float*)d_in[5];
    const float* g1_bl  = (const float*)d_in[6];
    const float* g1_Wr  = (const float*)d_in[7];
    const float* g1_br  = (const float*)d_in[8];
    const float* g1_We  = (const float*)d_in[9];
    const float* g1_att = (const float*)d_in[10];
    const float* g1_bias= (const float*)d_in[11];
    const float* g2_Wl  = (const float*)d_in[12];
    const float* g2_bl  = (const float*)d_in[13];
    const float* g2_Wr  = (const float*)d_in[14];
    const float* g2_br  = (const float*)d_in[15];
    const float* g2_We  = (const float*)d_in[16];
    const float* g2_att = (const float*)d_in[17];
    const float* g2_bias= (const float*)d_in[18];
    const float* int_W  = (const float*)d_in[19];
    const float* int_b  = (const float*)d_in[20];
    const float* imp_W  = (const float*)d_in[21];
    const float* imp_b  = (const float*)d_in[22];

    char* ws = (char*)d_ws;
    float* eapart  = (float*)(ws + OFF_EAPART);
    float* eamean  = (float*)(ws + OFF_EAMEAN);
    int*   partials= (int*)  (ws + OFF_PART);
    int*   cursor  = (int*)  (ws + OFF_CURSOR);
    int*   csrsrc  = (int*)  (ws + OFF_CSRSRC);
    int*   csreid  = (int*)  (ws + OFF_CSREID);
    int*   csrdst  = (int*)  (ws + OFF_CSRDST);
    float* accbuf  = (float*)(ws + OFF_ACC);
    float* denbuf  = (float*)(ws + OFF_DEN);
    int*   counts  = (int*)  (ws + OFF_COUNTS);
    float* h_a     = (float*)(ws + OFF_HA);
    float* h_b     = (float*)(ws + OFF_HB);
    unsigned short* xl = (unsigned short*)(ws + OFF_XL);
    float* xr      = (float*)(ws + OFF_XR);
    unsigned short* tab = (unsigned short*)(ws + OFF_TAB);
    float* P       = accbuf;                  // reuse acc region after finalize2
    float* outp    = (float*)d_out;

    constexpr int NT = (kTaug + 31) / 32;     // 13282 edge tiles
    constexpr int NGB = (kN + 63) / 64;       // 391 row blocks for MFMA gemms

    // zero acc + den + counts (one contiguous memset)
    hipMemsetAsync(ws + OFF_ACC, 0, MEMSET_BYTES, stream);

    // edge_attr mean + all weight-frag tables (2 launches)
    ea_colsum_part<<<1024, 256, 0, stream>>>(ea, eapart);
    ea_colsum_final<<<1, 256, 0, stream>>>(eapart, eamean);
    we_swizzle<<<32, 256, 0, stream>>>(g1_We, g2_We, tab);
    w_tables<<<288, 256, 0, stream>>>(emb_W, g1_Wl, g1_Wr, g2_Wl, g2_Wr, tab);

    // CSR by destination (self-loops included); counts pre-zeroed by memset
    count_edges<<<(kE + 255) / 256, 256, 0, stream>>>(ei, counts);
    scan_part<<<kNBLK, 256, 0, stream>>>(counts, cursor, partials);
    scan_mid<<<1, 128, 0, stream>>>(partials);
    scan_add<<<kNBLK, 256, 0, stream>>>(cursor, partials);
    scatter_kernel<<<(kTpad + 255) / 256, 256, 0, stream>>>(ei, cursor, csrsrc, csreid, csrdst);

    // node embedding (MFMA split-bf16, col-split grid)
    mfma_gemm_bias<128, 64, 2><<<NGB * 2, 256, 0, stream>>>(
        x, tab + T_EMBH, tab + T_EMBL, emb_b, h_a, kN);

    // ---- GAT layer 1 ----
    mfma_gemm_bias2<64, 256, 4><<<NGB * 4, 256, 0, stream>>>(
        h_a, tab + T_L1H, tab + T_L1L, tab + T_R1H, tab + T_R1L,
        g1_bl, g1_br, xl, xr, kN);
    edge_logit_aggr_kernel<<<NT, 256, 0, stream>>>(xl, xr, ea, eamean,
        tab + T_F1H, tab + T_F1L, g1_att, csrsrc, csrdst, csreid, accbuf, denbuf);
    gat_finalize<true><<<kN, 256, 0, stream>>>(accbuf, denbuf, g1_bias, h_b);

    // ---- GAT layer 2 (acc/den re-zeroed by finalize<true>) ----
    mfma_gemm_bias2<64, 256, 4><<<NGB * 4, 256, 0, stream>>>(
        h_b, tab + T_L2H, tab + T_L2L, tab + T_R2H, tab + T_R2L,
        g2_bl, g2_br, xl, xr, kN);
    edge_logit_aggr_kernel<<<NT, 256, 0, stream>>>(xl, xr, ea, eamean,
        tab + T_F2H, tab + T_F2L, g2_att, csrsrc, csrdst, csreid, accbuf, denbuf);
    gat_finalize<false><<<kN, 256, 0, stream>>>(accbuf, denbuf, g2_bias, h_a);

    // ---- edge heads (decomposed) ----
    node_head_kernel<<<(kN + 63) / 64, 256, 0, stream>>>(h_a, int_W, imp_W, P);
    edge_out_kernel<<<kE / 64, 256, 0, stream>>>(ea, ei, P, int_W, int_b, imp_W, imp_b, outp);
}